// Round 1
// baseline (1624.451 us; speedup 1.0000x reference)
//
#include <hip/hip_runtime.h>

#define T_DIM 1024
#define B_DIM 512
#define OBS_DIM 64
#define H_DIM 128
#define G3 384
#define A_DIM 16
#define CT 128
#define NCHUNK 8

typedef __bf16 bf16;
typedef __attribute__((ext_vector_type(8))) __bf16 bf16x8;
typedef __attribute__((ext_vector_type(4))) float f32x4;

#define MFMA(a, b, c) __builtin_amdgcn_mfma_f32_16x16x32_bf16((a), (b), (c), 0, 0, 0)

__device__ __forceinline__ float sigm(float x) { return 1.0f / (1.0f + __expf(-x)); }
__device__ __forceinline__ float tanh_f(float x) { return 1.0f - 2.0f / (__expf(2.0f * x) + 1.0f); }

// ---------------- prep: bf16 transposed weights + h_state init ----------------
__global__ __launch_bounds__(256) void prep_k(
    const float* __restrict__ hidden, const int* __restrict__ dones,
    const float* __restrict__ W_emb, const float* __restrict__ Wi,
    const float* __restrict__ Wh, const float* __restrict__ Wa1,
    const float* __restrict__ Wa2, const float* __restrict__ Wc1,
    const float* __restrict__ Wc2,
    bf16* __restrict__ wembT, bf16* __restrict__ wiT, bf16* __restrict__ whT,
    bf16* __restrict__ wa1T, bf16* __restrict__ wa2T, bf16* __restrict__ wc1T,
    bf16* __restrict__ wc2T, float* __restrict__ h_state) {
  int i = blockIdx.x * 256 + threadIdx.x;
  if (i < 8192) { int n = i / OBS_DIM, k = i % OBS_DIM; wembT[i] = (bf16)W_emb[k * H_DIM + n]; return; }
  i -= 8192;
  if (i < 49152) { int g = i / H_DIM, k = i % H_DIM; wiT[i] = (bf16)Wi[k * G3 + g]; return; }
  i -= 49152;
  if (i < 49152) { int g = i / H_DIM, k = i % H_DIM; whT[i] = (bf16)Wh[k * G3 + g]; return; }
  i -= 49152;
  if (i < 16384) { int n = i / H_DIM, k = i % H_DIM; wa1T[i] = (bf16)Wa1[k * H_DIM + n]; return; }
  i -= 16384;
  if (i < 2048) { int a = i / H_DIM, k = i % H_DIM; wa2T[i] = (bf16)Wa2[k * A_DIM + a]; return; }
  i -= 2048;
  if (i < 16384) { int n = i / H_DIM, k = i % H_DIM; wc1T[i] = (bf16)Wc1[k * H_DIM + n]; return; }
  i -= 16384;
  if (i < 2048) { int r = i / H_DIM, k = i % H_DIM; wc2T[i] = (r == 0) ? (bf16)Wc2[k] : (bf16)0.0f; return; }
  i -= 2048;
  if (i < 65536) { int b = i / H_DIM; h_state[i] = dones[b] ? 0.0f : hidden[i]; return; }
}

// ---------------- phase1: xi = relu(obs@W_emb+b_emb)@Wi + bi  (bf16 out) ------
__global__ __launch_bounds__(256) void phase1_k(
    const float* __restrict__ obs, const float* __restrict__ b_emb,
    const float* __restrict__ bi, const bf16* __restrict__ wembT,
    const bf16* __restrict__ wiT, bf16* __restrict__ xi, int row_base) {
  __shared__ __align__(16) bf16 lds[4][16][392];  // per-wave strip, padded stride
  int tid = threadIdx.x;
  int wave = tid >> 6, lane = tid & 63;
  int nl = lane & 15, q = lane >> 4;
  int r0 = blockIdx.x * 64 + wave * 16;          // chunk-local row
  long grow = (long)row_base + r0 + nl;          // global row for A loads

  // A fragments from obs (f32 -> bf16)
  bf16x8 ao[2];
  const float* op = obs + grow * OBS_DIM;
#pragma unroll
  for (int kb = 0; kb < 2; ++kb) {
    float4 v0 = *(const float4*)(op + kb * 32 + q * 8);
    float4 v1 = *(const float4*)(op + kb * 32 + q * 8 + 4);
    bf16x8 f;
    f[0] = (bf16)v0.x; f[1] = (bf16)v0.y; f[2] = (bf16)v0.z; f[3] = (bf16)v0.w;
    f[4] = (bf16)v1.x; f[5] = (bf16)v1.y; f[6] = (bf16)v1.z; f[7] = (bf16)v1.w;
    ao[kb] = f;
  }
  // emb = relu(obs@W_emb + b_emb) -> LDS strip [16][128]
#pragma unroll
  for (int nt = 0; nt < 8; ++nt) {
    f32x4 c = {0.f, 0.f, 0.f, 0.f};
#pragma unroll
    for (int kb = 0; kb < 2; ++kb) {
      bf16x8 bfr = *(const bf16x8*)(wembT + (nt * 16 + nl) * OBS_DIM + kb * 32 + q * 8);
      c = MFMA(ao[kb], bfr, c);
    }
    float be = b_emb[nt * 16 + nl];
#pragma unroll
    for (int r = 0; r < 4; ++r) {
      float v = c[r] + be;
      lds[wave][q * 4 + r][nt * 16 + nl] = (bf16)(v > 0.f ? v : 0.f);
    }
  }
  // reload emb as A fragments (same wave; compiler inserts lgkm waits)
  bf16x8 ae[4];
#pragma unroll
  for (int kb = 0; kb < 4; ++kb) ae[kb] = *(const bf16x8*)&lds[wave][nl][kb * 32 + q * 8];

  // xi = emb@Wi + bi -> LDS strip [16][384]
#pragma unroll
  for (int nt = 0; nt < 24; ++nt) {
    f32x4 c = {0.f, 0.f, 0.f, 0.f};
#pragma unroll
    for (int kb = 0; kb < 4; ++kb) {
      bf16x8 bfr = *(const bf16x8*)(wiT + (nt * 16 + nl) * H_DIM + kb * 32 + q * 8);
      c = MFMA(ae[kb], bfr, c);
    }
    float bv = bi[nt * 16 + nl];
#pragma unroll
    for (int r = 0; r < 4; ++r) lds[wave][q * 4 + r][nt * 16 + nl] = (bf16)(c[r] + bv);
  }
  // coalesced strip copy to global (16 rows x 384 bf16 contiguous = 12 KiB)
  bf16* dst = xi + (long)r0 * G3;
#pragma unroll
  for (int it = 0; it < 12; ++it) {
    int e0 = (it * 64 + lane) * 8;
    int row = e0 / G3, col = e0 % G3;
    *(int4*)(dst + e0) = *(const int4*)&lds[wave][row][col];
  }
}

// ---------------- scan: GRU over CT steps, 2 chains per block -----------------
// 8 waves x 512 threads. Wave w owns gate tiles {w, w+8, w+16} = complete
// (r,z,n) triple for h-dims 16w..16w+15 -> hh stays in registers (no LDS
// round trip). One barrier per step via double-buffered h tile. No global
// memory ops between per-step barriers (y buffered in LDS, flushed per 8
// steps) so the pre-barrier vmcnt(0) drain is amortized 16x.
__global__ __launch_bounds__(512) void scan_k(
    const bf16* __restrict__ xi, const int* __restrict__ dones,
    const float* __restrict__ bh_n, const bf16* __restrict__ whT,
    float* __restrict__ h_state, bf16* __restrict__ y,
    float* __restrict__ hidden_out, int chunk) {
  __shared__ __align__(16) bf16 hb[2][16][136];          // dbuf h tile (rows 0,1 live)
  __shared__ __align__(16) bf16 y_buf[2][8][2][H_DIM];   // dbuf 8-step y accumulator
  __shared__ __align__(16) bf16 xibuf[2][8][2][G3];      // dbuf 8-step xi stage
  __shared__ int dn[CT + 1][2];

  int tid = threadIdx.x;
  int wave = tid >> 6, lane = tid & 63;
  int nl = lane & 15, q = lane >> 4;
  int b0 = blockIdx.x * 2;
  int ch = q & 1;            // chain handled by this lane (q<2 active in gates)
  bool act = (q < 2);
  int d = wave * 16 + nl;    // h-dim owned by this lane

  for (int i = tid; i < 2 * 16 * 136; i += 512) ((bf16*)hb)[i] = (bf16)0.0f;
  for (int i = tid; i <= CT; i += 512) {
    int t = chunk * CT + i;
    dn[i][0] = (t < T_DIM) ? dones[t * B_DIM + b0] : 0;
    dn[i][1] = (t < T_DIM) ? dones[t * B_DIM + b0 + 1] : 0;
  }
  // stage first 8-step xi block
#pragma unroll
  for (int j = 0; j < 2; ++j) {
    int c16 = j * 512 + tid;
    if (c16 < 768) {
      int tt = c16 / 96, pos = c16 % 96;
      *(int4*)((bf16*)xibuf + tt * 2 * G3 + pos * 8) =
          *(const int4*)(xi + ((long)tt * B_DIM + b0) * G3 + pos * 8);
    }
  }
  __syncthreads();

  float hprev = 0.0f;
  if (act) {
    hprev = h_state[(b0 + ch) * H_DIM + d];
    hb[0][ch][d] = (bf16)hprev;
  }

  // Wh B-fragments: tiles {w, w+8, w+16} -> j indexes gate (0=r,1=z,2=n)
  bf16x8 wf[3][4];
#pragma unroll
  for (int j = 0; j < 3; ++j)
#pragma unroll
    for (int kb = 0; kb < 4; ++kb)
      wf[j][kb] = *(const bf16x8*)(whT + ((wave + 8 * j) * 16 + nl) * H_DIM + kb * 32 + q * 8);
  float bhn = bh_n[d];
  __syncthreads();

  int cur = 0;
  for (int tb = 0; tb < CT; tb += 8) {
    int gp = (tb >> 3) & 1;
    bool hv_pf = (tb + 8 < CT);
    int4 pf0, pf1;
#pragma unroll
    for (int ts = 0; ts < 8; ++ts) {
      int t = tb + ts;
      int p = t & 1;
      // h A-fragments (critical path) — issue first
      bf16x8 ha[4];
#pragma unroll
      for (int kb = 0; kb < 4; ++kb)
        ha[kb] = *(const bf16x8*)&hb[p][nl][kb * 32 + q * 8];
      if (ts == 0) {
        // flush previous group's y (only global stores in the loop)
        if (tb >= 8 && tid < 256) {
          int ts2 = tid >> 5, rem = tid & 31, ch2 = rem >> 4, k2 = rem & 15;
          *(int4*)(y + ((long)(tb - 8 + ts2) * B_DIM + b0 + ch2) * H_DIM + k2 * 8) =
              *(const int4*)&y_buf[gp ^ 1][ts2][ch2][k2 * 8];
        }
        // prefetch next group's xi into registers
        if (hv_pf) {
          { int tt = tid / 96, pos = tid % 96;
            pf0 = *(const int4*)(xi + ((long)(tb + 8 + tt) * B_DIM + b0) * G3 + pos * 8); }
          if (512 + tid < 768) {
            int c16 = 512 + tid; int tt = c16 / 96, pos = c16 % 96;
            pf1 = *(const int4*)(xi + ((long)(tb + 8 + tt) * B_DIM + b0) * G3 + pos * 8); }
        }
      }
      // xi for this step (LDS, independent of h)
      float xr = 0.f, xz = 0.f, xn = 0.f;
      if (act) {
        const bf16* xp = (const bf16*)xibuf + ((cur * 8 + ts) * 2 + ch) * G3 + d;
        xr = (float)xp[0]; xz = (float)xp[128]; xn = (float)xp[256];
      }
      // hh = h @ Wh for our gate triple
      f32x4 c[3];
#pragma unroll
      for (int j = 0; j < 3; ++j) c[j] = (f32x4){0.f, 0.f, 0.f, 0.f};
#pragma unroll
      for (int kb = 0; kb < 4; ++kb)
#pragma unroll
        for (int j = 0; j < 3; ++j) c[j] = MFMA(ha[kb], wf[j][kb], c[j]);
      if (ts == 7 && hv_pf) {
        int nb = cur ^ 1;
        { int tt = tid / 96, pos = tid % 96;
          *(int4*)((bf16*)xibuf + nb * (8 * 2 * G3) + tt * 2 * G3 + pos * 8) = pf0; }
        if (512 + tid < 768) {
          int c16 = 512 + tid; int tt = c16 / 96, pos = c16 % 96;
          *(int4*)((bf16*)xibuf + nb * (8 * 2 * G3) + tt * 2 * G3 + pos * 8) = pf1; }
      }
      // chain-1 hh lives in q==0 lanes' reg[1]; broadcast to q==1 lanes
      float s0 = __shfl(c[0][1], nl);
      float s1 = __shfl(c[1][1], nl);
      float s2 = __shfl(c[2][1], nl);
      float hr = ch ? s0 : c[0][0];
      float hz = ch ? s1 : c[1][0];
      float hn = ch ? s2 : c[2][0];
      float r = sigm(xr + hr);
      float z = sigm(xz + hz);
      float n = tanh_f(xn + r * (hn + bhn));
      float hnew = (1.f - z) * n + z * hprev;
      float heff = dn[t + 1][ch] ? 0.f : hnew;  // reset applied for NEXT step
      if (act) {
        y_buf[gp][ts][ch][d] = (bf16)hnew;
        hb[p ^ 1][ch][d] = (bf16)heff;
        if (chunk == NCHUNK - 1 && t == CT - 1)
          hidden_out[(b0 + ch) * H_DIM + d] = hnew;
      }
      hprev = heff;
      __syncthreads();
    }
    if (hv_pf) cur ^= 1;
  }
  // final y flush (last group wrote y_buf[1])
  if (tid < 256) {
    int ts2 = tid >> 5, rem = tid & 31, ch2 = rem >> 4, k2 = rem & 15;
    *(int4*)(y + ((long)(CT - 8 + ts2) * B_DIM + b0 + ch2) * H_DIM + k2 * 8) =
        *(const int4*)&y_buf[1][ts2][ch2][k2 * 8];
  }
  if (act) h_state[(b0 + ch) * H_DIM + d] = hprev;
}

// ---------------- heads: actor + critic from y (bf16 MFMA) -------------------
__global__ __launch_bounds__(256) void heads_k(
    const bf16* __restrict__ y, const float* __restrict__ ba1,
    const float* __restrict__ ba2, const float* __restrict__ bc1,
    const float* __restrict__ bc2, const bf16* __restrict__ wa1T,
    const bf16* __restrict__ wa2T, const bf16* __restrict__ wc1T,
    const bf16* __restrict__ wc2T, float* __restrict__ logits,
    float* __restrict__ v, int t_base) {
  __shared__ __align__(16) bf16 s_a1[4][16][136];
  __shared__ __align__(16) float s_o[4][16][16];
  __shared__ __align__(16) float s_v[4][16];
  int tid = threadIdx.x, wave = tid >> 6, lane = tid & 63;
  int nl = lane & 15, q = lane >> 4;
  int r0 = blockIdx.x * 64 + wave * 16;          // chunk-local row
  long gr0 = (long)t_base * B_DIM + r0;          // global row

  bf16x8 ya[4];
#pragma unroll
  for (int kb = 0; kb < 4; ++kb)
    ya[kb] = *(const bf16x8*)(y + (long)(r0 + nl) * H_DIM + kb * 32 + q * 8);

  // actor layer 1
#pragma unroll
  for (int nt = 0; nt < 8; ++nt) {
    f32x4 c = {0.f, 0.f, 0.f, 0.f};
#pragma unroll
    for (int kb = 0; kb < 4; ++kb) {
      bf16x8 bfr = *(const bf16x8*)(wa1T + (nt * 16 + nl) * H_DIM + kb * 32 + q * 8);
      c = MFMA(ya[kb], bfr, c);
    }
    float bv = ba1[nt * 16 + nl];
#pragma unroll
    for (int r = 0; r < 4; ++r) {
      float val = c[r] + bv;
      s_a1[wave][q * 4 + r][nt * 16 + nl] = (bf16)(val > 0.f ? val : 0.f);
    }
  }
  bf16x8 a1f[4];
#pragma unroll
  for (int kb = 0; kb < 4; ++kb) a1f[kb] = *(const bf16x8*)&s_a1[wave][nl][kb * 32 + q * 8];
  // logits
  {
    f32x4 c = {0.f, 0.f, 0.f, 0.f};
#pragma unroll
    for (int kb = 0; kb < 4; ++kb) {
      bf16x8 bfr = *(const bf16x8*)(wa2T + nl * H_DIM + kb * 32 + q * 8);
      c = MFMA(a1f[kb], bfr, c);
    }
    float bv = ba2[nl];
#pragma unroll
    for (int r = 0; r < 4; ++r) s_o[wave][q * 4 + r][nl] = c[r] + bv;
  }
  // critic layer 1 (reuse strip; ya already in regs)
#pragma unroll
  for (int nt = 0; nt < 8; ++nt) {
    f32x4 c = {0.f, 0.f, 0.f, 0.f};
#pragma unroll
    for (int kb = 0; kb < 4; ++kb) {
      bf16x8 bfr = *(const bf16x8*)(wc1T + (nt * 16 + nl) * H_DIM + kb * 32 + q * 8);
      c = MFMA(ya[kb], bfr, c);
    }
    float bv = bc1[nt * 16 + nl];
#pragma unroll
    for (int r = 0; r < 4; ++r) {
      float val = c[r] + bv;
      s_a1[wave][q * 4 + r][nt * 16 + nl] = (bf16)(val > 0.f ? val : 0.f);
    }
  }
  bf16x8 c1f[4];
#pragma unroll
  for (int kb = 0; kb < 4; ++kb) c1f[kb] = *(const bf16x8*)&s_a1[wave][nl][kb * 32 + q * 8];
  // v (Wc2 padded to 16 cols, col 0 real)
  {
    f32x4 c = {0.f, 0.f, 0.f, 0.f};
#pragma unroll
    for (int kb = 0; kb < 4; ++kb) {
      bf16x8 bfr = *(const bf16x8*)(wc2T + nl * H_DIM + kb * 32 + q * 8);
      c = MFMA(c1f[kb], bfr, c);
    }
    if (nl == 0) {
      float bv = bc2[0];
#pragma unroll
      for (int r = 0; r < 4; ++r) s_v[wave][q * 4 + r] = c[r] + bv;
    }
  }
  // coalesced writes
  *(int4*)(logits + gr0 * A_DIM + lane * 4) = *(const int4*)&s_o[wave][lane >> 2][(lane & 3) * 4];
  if (lane < 16) v[gr0 + lane] = s_v[wave][lane];
}

// ---------------- launch ------------------------------------------------------
extern "C" void kernel_launch(void* const* d_in, const int* in_sizes, int n_in,
                              void* d_out, int out_size, void* d_ws, size_t ws_size,
                              hipStream_t stream) {
  const float* hidden = (const float*)d_in[0];
  const float* obs    = (const float*)d_in[1];
  const int*   dones  = (const int*)d_in[2];
  const float* W_emb  = (const float*)d_in[3];
  const float* b_emb  = (const float*)d_in[4];
  const float* Wi     = (const float*)d_in[5];
  const float* bi     = (const float*)d_in[6];
  const float* Wh     = (const float*)d_in[7];
  const float* bh_n   = (const float*)d_in[8];
  const float* Wa1    = (const float*)d_in[9];
  const float* ba1    = (const float*)d_in[10];
  const float* Wa2    = (const float*)d_in[11];
  const float* ba2    = (const float*)d_in[12];
  const float* Wc1    = (const float*)d_in[13];
  const float* bc1    = (const float*)d_in[14];
  const float* Wc2    = (const float*)d_in[15];
  const float* bc2    = (const float*)d_in[16];

  float* out_hidden = (float*)d_out;
  float* out_logits = out_hidden + B_DIM * H_DIM;
  float* out_v      = out_logits + (long)T_DIM * B_DIM * A_DIM;

  char* ws = (char*)d_ws;
  bf16*  wembT   = (bf16*)(ws + 0);
  bf16*  wiT     = (bf16*)(ws + 16384);
  bf16*  whT     = (bf16*)(ws + 114688);
  bf16*  wa1T    = (bf16*)(ws + 212992);
  bf16*  wa2T    = (bf16*)(ws + 245760);
  bf16*  wc1T    = (bf16*)(ws + 249856);
  bf16*  wc2T    = (bf16*)(ws + 282624);
  float* h_state = (float*)(ws + 286720);
  bf16*  xi      = (bf16*)(ws + 548864);     // CT*B*384 bf16 = 50.3 MB
  bf16*  yb      = (bf16*)(ws + 50880512);   // CT*B*128 bf16 = 16.8 MB; total 67.7 MB

  prep_k<<<816, 256, 0, stream>>>(hidden, dones, W_emb, Wi, Wh, Wa1, Wa2, Wc1, Wc2,
                                  wembT, wiT, whT, wa1T, wa2T, wc1T, wc2T, h_state);
  for (int c = 0; c < NCHUNK; ++c) {
    phase1_k<<<(CT * B_DIM) / 64, 256, 0, stream>>>(obs, b_emb, bi, wembT, wiT, xi,
                                                    c * CT * B_DIM);
    scan_k<<<B_DIM / 2, 512, 0, stream>>>(xi, dones, bh_n, whT, h_state, yb,
                                          out_hidden, c);
    heads_k<<<(CT * B_DIM) / 64, 256, 0, stream>>>(yb, ba1, ba2, bc1, bc2, wa1T, wa2T,
                                                   wc1T, wc2T, out_logits, out_v, c * CT);
  }
  (void)in_sizes; (void)n_in; (void)out_size; (void)ws_size;
}

// Round 2
// 1471.979 us; speedup vs baseline: 1.1036x; 1.1036x over previous
//
#include <hip/hip_runtime.h>

#define T_DIM 1024
#define B_DIM 512
#define OBS_DIM 64
#define H_DIM 128
#define G3 384
#define A_DIM 16
#define CT 128
#define NCHUNK 8

typedef __bf16 bf16;
typedef __attribute__((ext_vector_type(8))) __bf16 bf16x8;
typedef __attribute__((ext_vector_type(4))) float f32x4;

#define MFMA(a, b, c) __builtin_amdgcn_mfma_f32_16x16x32_bf16((a), (b), (c), 0, 0, 0)

__device__ __forceinline__ float sigm(float x) { return 1.0f / (1.0f + __expf(-x)); }
__device__ __forceinline__ float tanh_f(float x) { return 1.0f - 2.0f / (__expf(2.0f * x) + 1.0f); }

// ---------------- prep: bf16 transposed weights + h_state init ----------------
__global__ __launch_bounds__(256) void prep_k(
    const float* __restrict__ hidden, const int* __restrict__ dones,
    const float* __restrict__ W_emb, const float* __restrict__ Wi,
    const float* __restrict__ Wh, const float* __restrict__ Wa1,
    const float* __restrict__ Wa2, const float* __restrict__ Wc1,
    const float* __restrict__ Wc2,
    bf16* __restrict__ wembT, bf16* __restrict__ wiT, bf16* __restrict__ whT,
    bf16* __restrict__ wa1T, bf16* __restrict__ wa2T, bf16* __restrict__ wc1T,
    bf16* __restrict__ wc2T, float* __restrict__ h_state) {
  int i = blockIdx.x * 256 + threadIdx.x;
  if (i < 8192) { int n = i / OBS_DIM, k = i % OBS_DIM; wembT[i] = (bf16)W_emb[k * H_DIM + n]; return; }
  i -= 8192;
  if (i < 49152) { int g = i / H_DIM, k = i % H_DIM; wiT[i] = (bf16)Wi[k * G3 + g]; return; }
  i -= 49152;
  if (i < 49152) { int g = i / H_DIM, k = i % H_DIM; whT[i] = (bf16)Wh[k * G3 + g]; return; }
  i -= 49152;
  if (i < 16384) { int n = i / H_DIM, k = i % H_DIM; wa1T[i] = (bf16)Wa1[k * H_DIM + n]; return; }
  i -= 16384;
  if (i < 2048) { int a = i / H_DIM, k = i % H_DIM; wa2T[i] = (bf16)Wa2[k * A_DIM + a]; return; }
  i -= 2048;
  if (i < 16384) { int n = i / H_DIM, k = i % H_DIM; wc1T[i] = (bf16)Wc1[k * H_DIM + n]; return; }
  i -= 16384;
  if (i < 2048) { int r = i / H_DIM, k = i % H_DIM; wc2T[i] = (r == 0) ? (bf16)Wc2[k] : (bf16)0.0f; return; }
  i -= 2048;
  if (i < 65536) { int b = i / H_DIM; h_state[i] = dones[b] ? 0.0f : hidden[i]; return; }
}

// ---------------- phase1: xi = relu(obs@W_emb+b_emb)@Wi + bi  (bf16 out) ------
// xi row layout (384 bf16 per (t,b)): [0..255] = (r,z) interleaved by dim
// (elem 2d = r_d, 2d+1 = z_d), [256..383] = n by dim. Lets scan read one b32
// + one u16 per lane instead of 3 scalar u16.
__global__ __launch_bounds__(256) void phase1_k(
    const float* __restrict__ obs, const float* __restrict__ b_emb,
    const float* __restrict__ bi, const bf16* __restrict__ wembT,
    const bf16* __restrict__ wiT, bf16* __restrict__ xi, int row_base) {
  __shared__ __align__(16) bf16 lds[4][16][392];  // per-wave strip, padded stride
  int tid = threadIdx.x;
  int wave = tid >> 6, lane = tid & 63;
  int nl = lane & 15, q = lane >> 4;
  int r0 = blockIdx.x * 64 + wave * 16;          // chunk-local row
  long grow = (long)row_base + r0 + nl;          // global row for A loads

  // A fragments from obs (f32 -> bf16)
  bf16x8 ao[2];
  const float* op = obs + grow * OBS_DIM;
#pragma unroll
  for (int kb = 0; kb < 2; ++kb) {
    float4 v0 = *(const float4*)(op + kb * 32 + q * 8);
    float4 v1 = *(const float4*)(op + kb * 32 + q * 8 + 4);
    bf16x8 f;
    f[0] = (bf16)v0.x; f[1] = (bf16)v0.y; f[2] = (bf16)v0.z; f[3] = (bf16)v0.w;
    f[4] = (bf16)v1.x; f[5] = (bf16)v1.y; f[6] = (bf16)v1.z; f[7] = (bf16)v1.w;
    ao[kb] = f;
  }
  // emb = relu(obs@W_emb + b_emb) -> LDS strip [16][128]
#pragma unroll
  for (int nt = 0; nt < 8; ++nt) {
    f32x4 c = {0.f, 0.f, 0.f, 0.f};
#pragma unroll
    for (int kb = 0; kb < 2; ++kb) {
      bf16x8 bfr = *(const bf16x8*)(wembT + (nt * 16 + nl) * OBS_DIM + kb * 32 + q * 8);
      c = MFMA(ao[kb], bfr, c);
    }
    float be = b_emb[nt * 16 + nl];
#pragma unroll
    for (int r = 0; r < 4; ++r) {
      float v = c[r] + be;
      lds[wave][q * 4 + r][nt * 16 + nl] = (bf16)(v > 0.f ? v : 0.f);
    }
  }
  // reload emb as A fragments (same wave; compiler inserts lgkm waits)
  bf16x8 ae[4];
#pragma unroll
  for (int kb = 0; kb < 4; ++kb) ae[kb] = *(const bf16x8*)&lds[wave][nl][kb * 32 + q * 8];

  // xi = emb@Wi + bi -> LDS strip [16][384], remapped gate layout
#pragma unroll
  for (int nt = 0; nt < 24; ++nt) {
    f32x4 c = {0.f, 0.f, 0.f, 0.f};
#pragma unroll
    for (int kb = 0; kb < 4; ++kb) {
      bf16x8 bfr = *(const bf16x8*)(wiT + (nt * 16 + nl) * H_DIM + kb * 32 + q * 8);
      c = MFMA(ae[kb], bfr, c);
    }
    float bv = bi[nt * 16 + nl];
    int gate = nt >> 3;                    // 0=r, 1=z, 2=n
    int dloc = (nt & 7) * 16 + nl;         // dim 0..127
    int pos = (gate < 2) ? (2 * dloc + gate) : (256 + dloc);
#pragma unroll
    for (int r = 0; r < 4; ++r) lds[wave][q * 4 + r][pos] = (bf16)(c[r] + bv);
  }
  // coalesced strip copy to global (16 rows x 384 bf16 contiguous = 12 KiB)
  bf16* dst = xi + (long)r0 * G3;
#pragma unroll
  for (int it = 0; it < 12; ++it) {
    int e0 = (it * 64 + lane) * 8;
    int row = e0 / G3, col = e0 % G3;
    *(int4*)(dst + e0) = *(const int4*)&lds[wave][row][col];
  }
}

// ---------------- scan: GRU over CT steps, 2 chains per block -----------------
// 4 waves x 256 threads, 1 wave/SIMD. Wave w owns 6 gate-tiles
// {g*8 + w + 4*hI : g=0..2, hI=0..1} -> every lane owns one (chain, dim) gate.
// h is written into A-rows {0,1,4,5,8,9,12,13} (4 copies of the 2 chains) so
// every q-group holds both chains' hh in its own D-regs: broadcast = cndmask,
// no ds_bpermute. Raw lgkmcnt(0)+s_barrier (no vmcnt drain) lets the per-step
// y store and the xi prefetch stay in flight across barriers.
__global__ __launch_bounds__(256, 1) void scan_k(
    const bf16* __restrict__ xi, const int* __restrict__ dones,
    const float* __restrict__ bh_n, const bf16* __restrict__ whT,
    float* __restrict__ h_state, bf16* __restrict__ y,
    float* __restrict__ hidden_out, int chunk) {
  __shared__ __align__(16) bf16 hb[2][16][136];          // dbuf h tile (replicated rows)
  __shared__ __align__(16) bf16 xibuf[2][8][2][400];     // dbuf 8-step xi stage (padded)
  __shared__ int dn[CT + 1][2];

  int tid = threadIdx.x;
  int wave = tid >> 6, lane = tid & 63;
  int nl = lane & 15, q = lane >> 4;
  int b0 = blockIdx.x * 2;
  int ch = q & 1;                 // chain owned by this lane
  int hsel = q >> 1;              // dim-block owned (0: +0, 1: +64)
  int dim = wave * 16 + (hsel << 6) + nl;

  for (int i = tid; i < 2 * 16 * 136; i += 256) ((bf16*)hb)[i] = (bf16)0.0f;
  for (int i = tid; i <= CT; i += 256) {
    int t = chunk * CT + i;
    dn[i][0] = (t < T_DIM) ? dones[t * B_DIM + b0] : 0;
    dn[i][1] = (t < T_DIM) ? dones[t * B_DIM + b0 + 1] : 0;
  }
  // per-thread staging slots (3 int4 per thread cover 8 steps x 2 chains x 384)
  int c0 = tid, c1 = 256 + tid, c2 = 512 + tid;
  int t0 = c0 / 96, p0 = c0 % 96, sc0 = p0 / 48, o0 = (p0 % 48) * 8;
  int t1 = c1 / 96, p1 = c1 % 96, sc1 = p1 / 48, o1 = (p1 % 48) * 8;
  int t2 = c2 / 96, p2 = c2 % 96, sc2 = p2 / 48, o2 = (p2 % 48) * 8;
  const long PSTR = (long)8 * B_DIM * G3;
  const bf16* pfs0 = xi + ((long)(8 + t0) * B_DIM + b0 + sc0) * G3 + o0;
  const bf16* pfs1 = xi + ((long)(8 + t1) * B_DIM + b0 + sc1) * G3 + o1;
  const bf16* pfs2 = xi + ((long)(8 + t2) * B_DIM + b0 + sc2) * G3 + o2;
  // stage group 0 into buf 0
  *(int4*)&xibuf[0][t0][sc0][o0] = *(const int4*)(xi + ((long)t0 * B_DIM + b0 + sc0) * G3 + o0);
  *(int4*)&xibuf[0][t1][sc1][o1] = *(const int4*)(xi + ((long)t1 * B_DIM + b0 + sc1) * G3 + o1);
  *(int4*)&xibuf[0][t2][sc2][o2] = *(const int4*)(xi + ((long)t2 * B_DIM + b0 + sc2) * G3 + o2);
  __syncthreads();

  float hprev = h_state[(b0 + ch) * H_DIM + dim];
  {
    bf16 h0 = (bf16)hprev;
    hb[0][0 + ch][dim] = h0;  hb[0][4 + ch][dim] = h0;
    hb[0][8 + ch][dim] = h0;  hb[0][12 + ch][dim] = h0;
  }
  // Wh B-fragments: tile(g,hI) = g*8 + wave + 4*hI, j = g*2+hI
  bf16x8 wf[6][4];
#pragma unroll
  for (int g = 0; g < 3; ++g)
#pragma unroll
    for (int hI = 0; hI < 2; ++hI)
#pragma unroll
      for (int kb = 0; kb < 4; ++kb)
        wf[g * 2 + hI][kb] =
            *(const bf16x8*)(whT + ((g * 8 + wave + 4 * hI) * 16 + nl) * H_DIM + kb * 32 + q * 8);
  float bhn = bh_n[dim];
  bf16* yp = y + (long)(b0 + ch) * H_DIM + dim;
  __syncthreads();

  int4 pfr0, pfr1, pfr2;

#define BAR()                                                                  \
  do {                                                                         \
    asm volatile("s_waitcnt lgkmcnt(0)" ::: "memory");                         \
    __builtin_amdgcn_sched_barrier(0);                                         \
    __builtin_amdgcn_s_barrier();                                              \
    __builtin_amdgcn_sched_barrier(0);                                         \
  } while (0)

#define MSTEP(HA, KB)                                                          \
  do {                                                                         \
    c0_ = MFMA(HA, wf[0][KB], c0_); c1_ = MFMA(HA, wf[1][KB], c1_);            \
    c2_ = MFMA(HA, wf[2][KB], c2_); c3_ = MFMA(HA, wf[3][KB], c3_);            \
    c4_ = MFMA(HA, wf[4][KB], c4_); c5_ = MFMA(HA, wf[5][KB], c5_);            \
  } while (0)

#define GSTEP(CUR, TS, TB, PF)                                                 \
  do {                                                                         \
    const int p_ = (TS) & 1;                                                   \
    bf16x8 ha0 = *(const bf16x8*)&hb[p_][nl][0 * 32 + q * 8];                  \
    bf16x8 ha1 = *(const bf16x8*)&hb[p_][nl][1 * 32 + q * 8];                  \
    bf16x8 ha2 = *(const bf16x8*)&hb[p_][nl][2 * 32 + q * 8];                  \
    bf16x8 ha3 = *(const bf16x8*)&hb[p_][nl][3 * 32 + q * 8];                  \
    const bf16* xrow_ = &xibuf[CUR][TS][ch][0];                                \
    unsigned urz_ = *(const unsigned*)(xrow_ + 2 * dim);                       \
    float xnv_ = (float)xrow_[256 + dim];                                      \
    int dnv_ = dn[(TB) + (TS) + 1][ch];                                        \
    if ((TS) == 0 && (PF)) {                                                   \
      pfr0 = *(const int4*)pfs0; pfs0 += PSTR;                                 \
      pfr1 = *(const int4*)pfs1; pfs1 += PSTR;                                 \
      pfr2 = *(const int4*)pfs2; pfs2 += PSTR;                                 \
    }                                                                          \
    f32x4 c0_ = {0.f, 0.f, 0.f, 0.f}, c1_ = {0.f, 0.f, 0.f, 0.f};             \
    f32x4 c2_ = {0.f, 0.f, 0.f, 0.f}, c3_ = {0.f, 0.f, 0.f, 0.f};             \
    f32x4 c4_ = {0.f, 0.f, 0.f, 0.f}, c5_ = {0.f, 0.f, 0.f, 0.f};             \
    MSTEP(ha0, 0); MSTEP(ha1, 1); MSTEP(ha2, 2); MSTEP(ha3, 3);                \
    if ((TS) == 7 && (PF)) {                                                   \
      *(int4*)&xibuf[(CUR) ^ 1][t0][sc0][o0] = pfr0;                           \
      *(int4*)&xibuf[(CUR) ^ 1][t1][sc1][o1] = pfr1;                           \
      *(int4*)&xibuf[(CUR) ^ 1][t2][sc2][o2] = pfr2;                           \
    }                                                                          \
    float hr_ = hsel ? (ch ? c1_[1] : c1_[0]) : (ch ? c0_[1] : c0_[0]);        \
    float hz_ = hsel ? (ch ? c3_[1] : c3_[0]) : (ch ? c2_[1] : c2_[0]);        \
    float hn_ = hsel ? (ch ? c5_[1] : c5_[0]) : (ch ? c4_[1] : c4_[0]);        \
    union { unsigned u; float f; } cvr_, cvz_;                                 \
    cvr_.u = urz_ << 16; cvz_.u = urz_ & 0xffff0000u;                          \
    float r_ = sigm(cvr_.f + hr_);                                             \
    float z_ = sigm(cvz_.f + hz_);                                             \
    float n_ = tanh_f(xnv_ + r_ * (hn_ + bhn));                                \
    float hnew_ = (1.0f - z_) * n_ + z_ * hprev;                               \
    float heff_ = dnv_ ? 0.0f : hnew_;                                         \
    *yp = (bf16)hnew_; yp += B_DIM * H_DIM;                                    \
    bf16 hbv_ = (bf16)heff_;                                                   \
    hb[p_ ^ 1][0 + ch][dim] = hbv_;  hb[p_ ^ 1][4 + ch][dim] = hbv_;           \
    hb[p_ ^ 1][8 + ch][dim] = hbv_;  hb[p_ ^ 1][12 + ch][dim] = hbv_;          \
    hprev = heff_;                                                             \
    BAR();                                                                     \
  } while (0)

  for (int tb = 0; tb < CT; tb += 16) {
    GSTEP(0, 0, tb, 1); GSTEP(0, 1, tb, 1); GSTEP(0, 2, tb, 1); GSTEP(0, 3, tb, 1);
    GSTEP(0, 4, tb, 1); GSTEP(0, 5, tb, 1); GSTEP(0, 6, tb, 1); GSTEP(0, 7, tb, 1);
    const int pfB = (tb + 16 < CT) ? 1 : 0;
    GSTEP(1, 0, tb + 8, pfB); GSTEP(1, 1, tb + 8, pfB); GSTEP(1, 2, tb + 8, pfB);
    GSTEP(1, 3, tb + 8, pfB); GSTEP(1, 4, tb + 8, pfB); GSTEP(1, 5, tb + 8, pfB);
    GSTEP(1, 6, tb + 8, pfB); GSTEP(1, 7, tb + 8, pfB);
  }
#undef GSTEP
#undef MSTEP
#undef BAR

  // heff(last) == hnew(last): dn[CT] for the final chunk is 0 (t >= T_DIM)
  h_state[(b0 + ch) * H_DIM + dim] = hprev;
  if (chunk == NCHUNK - 1) hidden_out[(b0 + ch) * H_DIM + dim] = hprev;
}

// ---------------- heads: actor + critic from y (bf16 MFMA) -------------------
__global__ __launch_bounds__(256) void heads_k(
    const bf16* __restrict__ y, const float* __restrict__ ba1,
    const float* __restrict__ ba2, const float* __restrict__ bc1,
    const float* __restrict__ bc2, const bf16* __restrict__ wa1T,
    const bf16* __restrict__ wa2T, const bf16* __restrict__ wc1T,
    const bf16* __restrict__ wc2T, float* __restrict__ logits,
    float* __restrict__ v, int t_base) {
  __shared__ __align__(16) bf16 s_a1[4][16][136];
  __shared__ __align__(16) float s_o[4][16][16];
  __shared__ __align__(16) float s_v[4][16];
  int tid = threadIdx.x, wave = tid >> 6, lane = tid & 63;
  int nl = lane & 15, q = lane >> 4;
  int r0 = blockIdx.x * 64 + wave * 16;          // chunk-local row
  long gr0 = (long)t_base * B_DIM + r0;          // global row

  bf16x8 ya[4];
#pragma unroll
  for (int kb = 0; kb < 4; ++kb)
    ya[kb] = *(const bf16x8*)(y + (long)(r0 + nl) * H_DIM + kb * 32 + q * 8);

  // actor layer 1
#pragma unroll
  for (int nt = 0; nt < 8; ++nt) {
    f32x4 c = {0.f, 0.f, 0.f, 0.f};
#pragma unroll
    for (int kb = 0; kb < 4; ++kb) {
      bf16x8 bfr = *(const bf16x8*)(wa1T + (nt * 16 + nl) * H_DIM + kb * 32 + q * 8);
      c = MFMA(ya[kb], bfr, c);
    }
    float bv = ba1[nt * 16 + nl];
#pragma unroll
    for (int r = 0; r < 4; ++r) {
      float val = c[r] + bv;
      s_a1[wave][q * 4 + r][nt * 16 + nl] = (bf16)(val > 0.f ? val : 0.f);
    }
  }
  bf16x8 a1f[4];
#pragma unroll
  for (int kb = 0; kb < 4; ++kb) a1f[kb] = *(const bf16x8*)&s_a1[wave][nl][kb * 32 + q * 8];
  // logits
  {
    f32x4 c = {0.f, 0.f, 0.f, 0.f};
#pragma unroll
    for (int kb = 0; kb < 4; ++kb) {
      bf16x8 bfr = *(const bf16x8*)(wa2T + nl * H_DIM + kb * 32 + q * 8);
      c = MFMA(a1f[kb], bfr, c);
    }
    float bv = ba2[nl];
#pragma unroll
    for (int r = 0; r < 4; ++r) s_o[wave][q * 4 + r][nl] = c[r] + bv;
  }
  // critic layer 1 (reuse strip; ya already in regs)
#pragma unroll
  for (int nt = 0; nt < 8; ++nt) {
    f32x4 c = {0.f, 0.f, 0.f, 0.f};
#pragma unroll
    for (int kb = 0; kb < 4; ++kb) {
      bf16x8 bfr = *(const bf16x8*)(wc1T + (nt * 16 + nl) * H_DIM + kb * 32 + q * 8);
      c = MFMA(ya[kb], bfr, c);
    }
    float bv = bc1[nt * 16 + nl];
#pragma unroll
    for (int r = 0; r < 4; ++r) {
      float val = c[r] + bv;
      s_a1[wave][q * 4 + r][nt * 16 + nl] = (bf16)(val > 0.f ? val : 0.f);
    }
  }
  bf16x8 c1f[4];
#pragma unroll
  for (int kb = 0; kb < 4; ++kb) c1f[kb] = *(const bf16x8*)&s_a1[wave][nl][kb * 32 + q * 8];
  // v (Wc2 padded to 16 cols, col 0 real)
  {
    f32x4 c = {0.f, 0.f, 0.f, 0.f};
#pragma unroll
    for (int kb = 0; kb < 4; ++kb) {
      bf16x8 bfr = *(const bf16x8*)(wc2T + nl * H_DIM + kb * 32 + q * 8);
      c = MFMA(c1f[kb], bfr, c);
    }
    if (nl == 0) {
      float bv = bc2[0];
#pragma unroll
      for (int r = 0; r < 4; ++r) s_v[wave][q * 4 + r] = c[r] + bv;
    }
  }
  // coalesced writes
  *(int4*)(logits + gr0 * A_DIM + lane * 4) = *(const int4*)&s_o[wave][lane >> 2][(lane & 3) * 4];
  if (lane < 16) v[gr0 + lane] = s_v[wave][lane];
}

// ---------------- launch ------------------------------------------------------
extern "C" void kernel_launch(void* const* d_in, const int* in_sizes, int n_in,
                              void* d_out, int out_size, void* d_ws, size_t ws_size,
                              hipStream_t stream) {
  const float* hidden = (const float*)d_in[0];
  const float* obs    = (const float*)d_in[1];
  const int*   dones  = (const int*)d_in[2];
  const float* W_emb  = (const float*)d_in[3];
  const float* b_emb  = (const float*)d_in[4];
  const float* Wi     = (const float*)d_in[5];
  const float* bi     = (const float*)d_in[6];
  const float* Wh     = (const float*)d_in[7];
  const float* bh_n   = (const float*)d_in[8];
  const float* Wa1    = (const float*)d_in[9];
  const float* ba1    = (const float*)d_in[10];
  const float* Wa2    = (const float*)d_in[11];
  const float* ba2    = (const float*)d_in[12];
  const float* Wc1    = (const float*)d_in[13];
  const float* bc1    = (const float*)d_in[14];
  const float* Wc2    = (const float*)d_in[15];
  const float* bc2    = (const float*)d_in[16];

  float* out_hidden = (float*)d_out;
  float* out_logits = out_hidden + B_DIM * H_DIM;
  float* out_v      = out_logits + (long)T_DIM * B_DIM * A_DIM;

  char* ws = (char*)d_ws;
  bf16*  wembT   = (bf16*)(ws + 0);
  bf16*  wiT     = (bf16*)(ws + 16384);
  bf16*  whT     = (bf16*)(ws + 114688);
  bf16*  wa1T    = (bf16*)(ws + 212992);
  bf16*  wa2T    = (bf16*)(ws + 245760);
  bf16*  wc1T    = (bf16*)(ws + 249856);
  bf16*  wc2T    = (bf16*)(ws + 282624);
  float* h_state = (float*)(ws + 286720);
  bf16*  xi      = (bf16*)(ws + 548864);     // CT*B*384 bf16 = 50.3 MB
  bf16*  yb      = (bf16*)(ws + 50880512);   // CT*B*128 bf16 = 16.8 MB; total 67.7 MB

  prep_k<<<816, 256, 0, stream>>>(hidden, dones, W_emb, Wi, Wh, Wa1, Wa2, Wc1, Wc2,
                                  wembT, wiT, whT, wa1T, wa2T, wc1T, wc2T, h_state);
  for (int c = 0; c < NCHUNK; ++c) {
    phase1_k<<<(CT * B_DIM) / 64, 256, 0, stream>>>(obs, b_emb, bi, wembT, wiT, xi,
                                                    c * CT * B_DIM);
    scan_k<<<B_DIM / 2, 256, 0, stream>>>(xi, dones, bh_n, whT, h_state, yb,
                                          out_hidden, c);
    heads_k<<<(CT * B_DIM) / 64, 256, 0, stream>>>(yb, ba1, ba2, bc1, bc2, wa1T, wa2T,
                                                   wc1T, wc2T, out_logits, out_v, c * CT);
  }
  (void)in_sizes; (void)n_in; (void)out_size; (void)ws_size;
}

// Round 3
// 1038.528 us; speedup vs baseline: 1.5642x; 1.4174x over previous
//
#include <hip/hip_runtime.h>

#define T_DIM 1024
#define B_DIM 512
#define OBS_DIM 64
#define H_DIM 128
#define G3 384
#define A_DIM 16
#define CT 128
#define NCHUNK 8

typedef __bf16 bf16;
typedef __attribute__((ext_vector_type(8))) __bf16 bf16x8;
typedef __attribute__((ext_vector_type(4))) float f32x4;

#define MFMA(a, b, c) __builtin_amdgcn_mfma_f32_16x16x32_bf16((a), (b), (c), 0, 0, 0)

__device__ __forceinline__ float sigm(float x) { return 1.0f / (1.0f + __expf(-x)); }
__device__ __forceinline__ float tanh_f(float x) { return 1.0f - 2.0f / (__expf(2.0f * x) + 1.0f); }

// ---------------- prep: bf16 transposed weights + h_state init ----------------
__global__ __launch_bounds__(256) void prep_k(
    const float* __restrict__ hidden, const int* __restrict__ dones,
    const float* __restrict__ W_emb, const float* __restrict__ Wi,
    const float* __restrict__ Wh, const float* __restrict__ Wa1,
    const float* __restrict__ Wa2, const float* __restrict__ Wc1,
    const float* __restrict__ Wc2,
    bf16* __restrict__ wembT, bf16* __restrict__ wiT, bf16* __restrict__ whT,
    bf16* __restrict__ wa1T, bf16* __restrict__ wa2T, bf16* __restrict__ wc1T,
    bf16* __restrict__ wc2T, float* __restrict__ h_state) {
  int i = blockIdx.x * 256 + threadIdx.x;
  if (i < 8192) { int n = i / OBS_DIM, k = i % OBS_DIM; wembT[i] = (bf16)W_emb[k * H_DIM + n]; return; }
  i -= 8192;
  if (i < 49152) { int g = i / H_DIM, k = i % H_DIM; wiT[i] = (bf16)Wi[k * G3 + g]; return; }
  i -= 49152;
  if (i < 49152) { int g = i / H_DIM, k = i % H_DIM; whT[i] = (bf16)Wh[k * G3 + g]; return; }
  i -= 49152;
  if (i < 16384) { int n = i / H_DIM, k = i % H_DIM; wa1T[i] = (bf16)Wa1[k * H_DIM + n]; return; }
  i -= 16384;
  if (i < 2048) { int a = i / H_DIM, k = i % H_DIM; wa2T[i] = (bf16)Wa2[k * A_DIM + a]; return; }
  i -= 2048;
  if (i < 16384) { int n = i / H_DIM, k = i % H_DIM; wc1T[i] = (bf16)Wc1[k * H_DIM + n]; return; }
  i -= 16384;
  if (i < 2048) { int r = i / H_DIM, k = i % H_DIM; wc2T[i] = (r == 0) ? (bf16)Wc2[k] : (bf16)0.0f; return; }
  i -= 2048;
  if (i < 65536) { int b = i / H_DIM; h_state[i] = dones[b] ? 0.0f : hidden[i]; return; }
}

// ================= role bodies (share one 50176-B LDS block) =================

// ---- phase1 body: xi = relu(obs@W_emb+b_emb)@Wi + bi (gate-remapped bf16) ----
__device__ __forceinline__ void phase1_body(
    char* smem, int bid, const float* __restrict__ obs,
    const float* __restrict__ b_emb, const float* __restrict__ bi,
    const bf16* __restrict__ wembT, const bf16* __restrict__ wiT,
    bf16* __restrict__ xi, int row_base) {
  bf16 (*lds)[16][392] = (bf16(*)[16][392])smem;   // [4 waves][16][392]
  int tid = threadIdx.x;
  int wave = tid >> 6, lane = tid & 63;
  int nl = lane & 15, q = lane >> 4;
  int r0 = bid * 64 + wave * 16;                 // chunk-local row
  long grow = (long)row_base + r0 + nl;          // global row for A loads

  bf16x8 ao[2];
  const float* op = obs + grow * OBS_DIM;
#pragma unroll
  for (int kb = 0; kb < 2; ++kb) {
    float4 v0 = *(const float4*)(op + kb * 32 + q * 8);
    float4 v1 = *(const float4*)(op + kb * 32 + q * 8 + 4);
    bf16x8 f;
    f[0] = (bf16)v0.x; f[1] = (bf16)v0.y; f[2] = (bf16)v0.z; f[3] = (bf16)v0.w;
    f[4] = (bf16)v1.x; f[5] = (bf16)v1.y; f[6] = (bf16)v1.z; f[7] = (bf16)v1.w;
    ao[kb] = f;
  }
#pragma unroll
  for (int nt = 0; nt < 8; ++nt) {
    f32x4 c = {0.f, 0.f, 0.f, 0.f};
#pragma unroll
    for (int kb = 0; kb < 2; ++kb) {
      bf16x8 bfr = *(const bf16x8*)(wembT + (nt * 16 + nl) * OBS_DIM + kb * 32 + q * 8);
      c = MFMA(ao[kb], bfr, c);
    }
    float be = b_emb[nt * 16 + nl];
#pragma unroll
    for (int r = 0; r < 4; ++r) {
      float v = c[r] + be;
      lds[wave][q * 4 + r][nt * 16 + nl] = (bf16)(v > 0.f ? v : 0.f);
    }
  }
  bf16x8 ae[4];
#pragma unroll
  for (int kb = 0; kb < 4; ++kb) ae[kb] = *(const bf16x8*)&lds[wave][nl][kb * 32 + q * 8];

#pragma unroll
  for (int nt = 0; nt < 24; ++nt) {
    f32x4 c = {0.f, 0.f, 0.f, 0.f};
#pragma unroll
    for (int kb = 0; kb < 4; ++kb) {
      bf16x8 bfr = *(const bf16x8*)(wiT + (nt * 16 + nl) * H_DIM + kb * 32 + q * 8);
      c = MFMA(ae[kb], bfr, c);
    }
    float bv = bi[nt * 16 + nl];
    int gate = nt >> 3;                    // 0=r, 1=z, 2=n
    int dloc = (nt & 7) * 16 + nl;         // dim 0..127
    int pos = (gate < 2) ? (2 * dloc + gate) : (256 + dloc);
#pragma unroll
    for (int r = 0; r < 4; ++r) lds[wave][q * 4 + r][pos] = (bf16)(c[r] + bv);
  }
  bf16* dst = xi + (long)r0 * G3;
#pragma unroll
  for (int it = 0; it < 12; ++it) {
    int e0 = (it * 64 + lane) * 8;
    int row = e0 / G3, col = e0 % G3;
    *(int4*)(dst + e0) = *(const int4*)&lds[wave][row][col];
  }
}

// ---- scan body: GRU over CT steps, 2 chains per block (1 block/CU) ----------
__device__ __forceinline__ void scan_body(
    char* smem, int bid, const bf16* __restrict__ xi,
    const int* __restrict__ dones, const float* __restrict__ bh_n,
    const bf16* __restrict__ whT, float* __restrict__ h_state,
    bf16* __restrict__ y, float* __restrict__ hidden_out, int chunk) {
  bf16 (*hb)[16][136]      = (bf16(*)[16][136])smem;              // 8704 B
  bf16 (*xibuf)[8][2][400] = (bf16(*)[8][2][400])(smem + 8704);   // 25600 B
  int  (*dn)[2]            = (int(*)[2])(smem + 34304);           // 1032 B

  __builtin_amdgcn_s_setprio(1);   // win SIMD arbitration vs worker waves

  int tid = threadIdx.x;
  int wave = tid >> 6, lane = tid & 63;
  int nl = lane & 15, q = lane >> 4;
  int b0 = bid * 2;
  int ch = q & 1;
  int hsel = q >> 1;
  int dim = wave * 16 + (hsel << 6) + nl;

  for (int i = tid; i < 2 * 16 * 136; i += 256) ((bf16*)hb)[i] = (bf16)0.0f;
  for (int i = tid; i <= CT; i += 256) {
    int t = chunk * CT + i;
    dn[i][0] = (t < T_DIM) ? dones[t * B_DIM + b0] : 0;
    dn[i][1] = (t < T_DIM) ? dones[t * B_DIM + b0 + 1] : 0;
  }
  int c0 = tid, c1 = 256 + tid, c2 = 512 + tid;
  int t0 = c0 / 96, p0 = c0 % 96, sc0 = p0 / 48, o0 = (p0 % 48) * 8;
  int t1 = c1 / 96, p1 = c1 % 96, sc1 = p1 / 48, o1 = (p1 % 48) * 8;
  int t2 = c2 / 96, p2 = c2 % 96, sc2 = p2 / 48, o2 = (p2 % 48) * 8;
  const long PSTR = (long)8 * B_DIM * G3;
  const bf16* pfs0 = xi + ((long)(8 + t0) * B_DIM + b0 + sc0) * G3 + o0;
  const bf16* pfs1 = xi + ((long)(8 + t1) * B_DIM + b0 + sc1) * G3 + o1;
  const bf16* pfs2 = xi + ((long)(8 + t2) * B_DIM + b0 + sc2) * G3 + o2;
  *(int4*)&xibuf[0][t0][sc0][o0] = *(const int4*)(xi + ((long)t0 * B_DIM + b0 + sc0) * G3 + o0);
  *(int4*)&xibuf[0][t1][sc1][o1] = *(const int4*)(xi + ((long)t1 * B_DIM + b0 + sc1) * G3 + o1);
  *(int4*)&xibuf[0][t2][sc2][o2] = *(const int4*)(xi + ((long)t2 * B_DIM + b0 + sc2) * G3 + o2);
  __syncthreads();

  float hprev = h_state[(b0 + ch) * H_DIM + dim];
  {
    bf16 h0 = (bf16)hprev;
    hb[0][0 + ch][dim] = h0;  hb[0][4 + ch][dim] = h0;
    hb[0][8 + ch][dim] = h0;  hb[0][12 + ch][dim] = h0;
  }
  bf16x8 wf[6][4];
#pragma unroll
  for (int g = 0; g < 3; ++g)
#pragma unroll
    for (int hI = 0; hI < 2; ++hI)
#pragma unroll
      for (int kb = 0; kb < 4; ++kb)
        wf[g * 2 + hI][kb] =
            *(const bf16x8*)(whT + ((g * 8 + wave + 4 * hI) * 16 + nl) * H_DIM + kb * 32 + q * 8);
  float bhn = bh_n[dim];
  bf16* yp = y + (long)(b0 + ch) * H_DIM + dim;
  __syncthreads();

  int4 pfr0, pfr1, pfr2;

#define BAR()                                                                  \
  do {                                                                         \
    asm volatile("s_waitcnt lgkmcnt(0)" ::: "memory");                         \
    __builtin_amdgcn_sched_barrier(0);                                         \
    __builtin_amdgcn_s_barrier();                                              \
    __builtin_amdgcn_sched_barrier(0);                                         \
  } while (0)

#define MSTEP(HA, KB)                                                          \
  do {                                                                         \
    c0_ = MFMA(HA, wf[0][KB], c0_); c1_ = MFMA(HA, wf[1][KB], c1_);            \
    c2_ = MFMA(HA, wf[2][KB], c2_); c3_ = MFMA(HA, wf[3][KB], c3_);            \
    c4_ = MFMA(HA, wf[4][KB], c4_); c5_ = MFMA(HA, wf[5][KB], c5_);            \
  } while (0)

#define GSTEP(CUR, TS, TB, PF)                                                 \
  do {                                                                         \
    const int p_ = (TS) & 1;                                                   \
    bf16x8 ha0 = *(const bf16x8*)&hb[p_][nl][0 * 32 + q * 8];                  \
    bf16x8 ha1 = *(const bf16x8*)&hb[p_][nl][1 * 32 + q * 8];                  \
    bf16x8 ha2 = *(const bf16x8*)&hb[p_][nl][2 * 32 + q * 8];                  \
    bf16x8 ha3 = *(const bf16x8*)&hb[p_][nl][3 * 32 + q * 8];                  \
    const bf16* xrow_ = &xibuf[CUR][TS][ch][0];                                \
    unsigned urz_ = *(const unsigned*)(xrow_ + 2 * dim);                       \
    float xnv_ = (float)xrow_[256 + dim];                                      \
    int dnv_ = dn[(TB) + (TS) + 1][ch];                                        \
    if ((TS) == 0 && (PF)) {                                                   \
      pfr0 = *(const int4*)pfs0; pfs0 += PSTR;                                 \
      pfr1 = *(const int4*)pfs1; pfs1 += PSTR;                                 \
      pfr2 = *(const int4*)pfs2; pfs2 += PSTR;                                 \
    }                                                                          \
    f32x4 c0_ = {0.f, 0.f, 0.f, 0.f}, c1_ = {0.f, 0.f, 0.f, 0.f};             \
    f32x4 c2_ = {0.f, 0.f, 0.f, 0.f}, c3_ = {0.f, 0.f, 0.f, 0.f};             \
    f32x4 c4_ = {0.f, 0.f, 0.f, 0.f}, c5_ = {0.f, 0.f, 0.f, 0.f};             \
    MSTEP(ha0, 0); MSTEP(ha1, 1); MSTEP(ha2, 2); MSTEP(ha3, 3);                \
    if ((TS) == 7 && (PF)) {                                                   \
      *(int4*)&xibuf[(CUR) ^ 1][t0][sc0][o0] = pfr0;                           \
      *(int4*)&xibuf[(CUR) ^ 1][t1][sc1][o1] = pfr1;                           \
      *(int4*)&xibuf[(CUR) ^ 1][t2][sc2][o2] = pfr2;                           \
    }                                                                          \
    float hr_ = hsel ? (ch ? c1_[1] : c1_[0]) : (ch ? c0_[1] : c0_[0]);        \
    float hz_ = hsel ? (ch ? c3_[1] : c3_[0]) : (ch ? c2_[1] : c2_[0]);        \
    float hn_ = hsel ? (ch ? c5_[1] : c5_[0]) : (ch ? c4_[1] : c4_[0]);        \
    union { unsigned u; float f; } cvr_, cvz_;                                 \
    cvr_.u = urz_ << 16; cvz_.u = urz_ & 0xffff0000u;                          \
    float r_ = sigm(cvr_.f + hr_);                                             \
    float z_ = sigm(cvz_.f + hz_);                                             \
    float n_ = tanh_f(xnv_ + r_ * (hn_ + bhn));                                \
    float hnew_ = (1.0f - z_) * n_ + z_ * hprev;                               \
    float heff_ = dnv_ ? 0.0f : hnew_;                                         \
    *yp = (bf16)hnew_; yp += B_DIM * H_DIM;                                    \
    bf16 hbv_ = (bf16)heff_;                                                   \
    hb[p_ ^ 1][0 + ch][dim] = hbv_;  hb[p_ ^ 1][4 + ch][dim] = hbv_;           \
    hb[p_ ^ 1][8 + ch][dim] = hbv_;  hb[p_ ^ 1][12 + ch][dim] = hbv_;          \
    hprev = heff_;                                                             \
    BAR();                                                                     \
  } while (0)

  for (int tb = 0; tb < CT; tb += 16) {
    GSTEP(0, 0, tb, 1); GSTEP(0, 1, tb, 1); GSTEP(0, 2, tb, 1); GSTEP(0, 3, tb, 1);
    GSTEP(0, 4, tb, 1); GSTEP(0, 5, tb, 1); GSTEP(0, 6, tb, 1); GSTEP(0, 7, tb, 1);
    const int pfB = (tb + 16 < CT) ? 1 : 0;
    GSTEP(1, 0, tb + 8, pfB); GSTEP(1, 1, tb + 8, pfB); GSTEP(1, 2, tb + 8, pfB);
    GSTEP(1, 3, tb + 8, pfB); GSTEP(1, 4, tb + 8, pfB); GSTEP(1, 5, tb + 8, pfB);
    GSTEP(1, 6, tb + 8, pfB); GSTEP(1, 7, tb + 8, pfB);
  }
#undef GSTEP
#undef MSTEP
#undef BAR
  __builtin_amdgcn_s_setprio(0);

  h_state[(b0 + ch) * H_DIM + dim] = hprev;
  if (chunk == NCHUNK - 1) hidden_out[(b0 + ch) * H_DIM + dim] = hprev;
}

// ---- heads body: actor + critic from y ---------------------------------------
__device__ __forceinline__ void heads_body(
    char* smem, int bid, const bf16* __restrict__ y,
    const float* __restrict__ ba1, const float* __restrict__ ba2,
    const float* __restrict__ bc1, const float* __restrict__ bc2,
    const bf16* __restrict__ wa1T, const bf16* __restrict__ wa2T,
    const bf16* __restrict__ wc1T, const bf16* __restrict__ wc2T,
    float* __restrict__ logits, float* __restrict__ v, int t_base) {
  bf16  (*s_a1)[16][136] = (bf16(*)[16][136])smem;           // 17408 B
  float (*s_o)[16][16]   = (float(*)[16][16])(smem + 17408); // 4096 B
  float (*s_v)[16]       = (float(*)[16])(smem + 21504);     // 256 B
  int tid = threadIdx.x, wave = tid >> 6, lane = tid & 63;
  int nl = lane & 15, q = lane >> 4;
  int r0 = bid * 64 + wave * 16;
  long gr0 = (long)t_base * B_DIM + r0;

  bf16x8 ya[4];
#pragma unroll
  for (int kb = 0; kb < 4; ++kb)
    ya[kb] = *(const bf16x8*)(y + (long)(r0 + nl) * H_DIM + kb * 32 + q * 8);

#pragma unroll
  for (int nt = 0; nt < 8; ++nt) {
    f32x4 c = {0.f, 0.f, 0.f, 0.f};
#pragma unroll
    for (int kb = 0; kb < 4; ++kb) {
      bf16x8 bfr = *(const bf16x8*)(wa1T + (nt * 16 + nl) * H_DIM + kb * 32 + q * 8);
      c = MFMA(ya[kb], bfr, c);
    }
    float bv = ba1[nt * 16 + nl];
#pragma unroll
    for (int r = 0; r < 4; ++r) {
      float val = c[r] + bv;
      s_a1[wave][q * 4 + r][nt * 16 + nl] = (bf16)(val > 0.f ? val : 0.f);
    }
  }
  bf16x8 a1f[4];
#pragma unroll
  for (int kb = 0; kb < 4; ++kb) a1f[kb] = *(const bf16x8*)&s_a1[wave][nl][kb * 32 + q * 8];
  {
    f32x4 c = {0.f, 0.f, 0.f, 0.f};
#pragma unroll
    for (int kb = 0; kb < 4; ++kb) {
      bf16x8 bfr = *(const bf16x8*)(wa2T + nl * H_DIM + kb * 32 + q * 8);
      c = MFMA(a1f[kb], bfr, c);
    }
    float bv = ba2[nl];
#pragma unroll
    for (int r = 0; r < 4; ++r) s_o[wave][q * 4 + r][nl] = c[r] + bv;
  }
#pragma unroll
  for (int nt = 0; nt < 8; ++nt) {
    f32x4 c = {0.f, 0.f, 0.f, 0.f};
#pragma unroll
    for (int kb = 0; kb < 4; ++kb) {
      bf16x8 bfr = *(const bf16x8*)(wc1T + (nt * 16 + nl) * H_DIM + kb * 32 + q * 8);
      c = MFMA(ya[kb], bfr, c);
    }
    float bv = bc1[nt * 16 + nl];
#pragma unroll
    for (int r = 0; r < 4; ++r) {
      float val = c[r] + bv;
      s_a1[wave][q * 4 + r][nt * 16 + nl] = (bf16)(val > 0.f ? val : 0.f);
    }
  }
  bf16x8 c1f[4];
#pragma unroll
  for (int kb = 0; kb < 4; ++kb) c1f[kb] = *(const bf16x8*)&s_a1[wave][nl][kb * 32 + q * 8];
  {
    f32x4 c = {0.f, 0.f, 0.f, 0.f};
#pragma unroll
    for (int kb = 0; kb < 4; ++kb) {
      bf16x8 bfr = *(const bf16x8*)(wc2T + nl * H_DIM + kb * 32 + q * 8);
      c = MFMA(c1f[kb], bfr, c);
    }
    if (nl == 0) {
      float bv = bc2[0];
#pragma unroll
      for (int r = 0; r < 4; ++r) s_v[wave][q * 4 + r] = c[r] + bv;
    }
  }
  *(int4*)(logits + gr0 * A_DIM + lane * 4) = *(const int4*)&s_o[wave][lane >> 2][(lane & 3) * 4];
  if (lane < 16) v[gr0 + lane] = s_v[wave][lane];
}

// ---- fused pipeline kernel: scan(cs) ∥ phase1(cs+1) ∥ heads(cs-1) ------------
__global__ __launch_bounds__(256, 1) void fused_k(
    const float* __restrict__ obs, const float* __restrict__ b_emb,
    const float* __restrict__ bi, const bf16* __restrict__ wembT,
    const bf16* __restrict__ wiT, bf16* __restrict__ xi0, bf16* __restrict__ xi1,
    const int* __restrict__ dones, const float* __restrict__ bh_n,
    const bf16* __restrict__ whT, float* __restrict__ h_state,
    bf16* __restrict__ y0, bf16* __restrict__ y1, float* __restrict__ hidden_out,
    const float* __restrict__ ba1, const float* __restrict__ ba2,
    const float* __restrict__ bc1, const float* __restrict__ bc2,
    const bf16* __restrict__ wa1T, const bf16* __restrict__ wa2T,
    const bf16* __restrict__ wc1T, const bf16* __restrict__ wc2T,
    float* __restrict__ logits, float* __restrict__ v, int cs) {
  __shared__ __align__(16) char smem[50176];
  int bid = blockIdx.x;
  if (bid < 256) {
    if (cs >= 0 && cs < NCHUNK)
      scan_body(smem, bid, (cs & 1) ? xi1 : xi0, dones, bh_n, whT, h_state,
                (cs & 1) ? y1 : y0, hidden_out, cs);
    return;
  }
  if (bid < 1280) {
    int cp = cs + 1;
    if (cp >= 0 && cp < NCHUNK)
      phase1_body(smem, bid - 256, obs, b_emb, bi, wembT, wiT,
                  (cp & 1) ? xi1 : xi0, cp * CT * B_DIM);
    return;
  }
  {
    int ch2 = cs - 1;
    if (ch2 >= 0 && ch2 < NCHUNK)
      heads_body(smem, bid - 1280, (ch2 & 1) ? y1 : y0, ba1, ba2, bc1, bc2,
                 wa1T, wa2T, wc1T, wc2T, logits, v, ch2 * CT);
  }
}

// ---------------- launch ------------------------------------------------------
extern "C" void kernel_launch(void* const* d_in, const int* in_sizes, int n_in,
                              void* d_out, int out_size, void* d_ws, size_t ws_size,
                              hipStream_t stream) {
  const float* hidden = (const float*)d_in[0];
  const float* obs    = (const float*)d_in[1];
  const int*   dones  = (const int*)d_in[2];
  const float* W_emb  = (const float*)d_in[3];
  const float* b_emb  = (const float*)d_in[4];
  const float* Wi     = (const float*)d_in[5];
  const float* bi     = (const float*)d_in[6];
  const float* Wh     = (const float*)d_in[7];
  const float* bh_n   = (const float*)d_in[8];
  const float* Wa1    = (const float*)d_in[9];
  const float* ba1    = (const float*)d_in[10];
  const float* Wa2    = (const float*)d_in[11];
  const float* ba2    = (const float*)d_in[12];
  const float* Wc1    = (const float*)d_in[13];
  const float* bc1    = (const float*)d_in[14];
  const float* Wc2    = (const float*)d_in[15];
  const float* bc2    = (const float*)d_in[16];

  float* out_hidden = (float*)d_out;
  float* out_logits = out_hidden + B_DIM * H_DIM;
  float* out_v      = out_logits + (long)T_DIM * B_DIM * A_DIM;

  char* ws = (char*)d_ws;
  bf16*  wembT   = (bf16*)(ws + 0);
  bf16*  wiT     = (bf16*)(ws + 16384);
  bf16*  whT     = (bf16*)(ws + 114688);
  bf16*  wa1T    = (bf16*)(ws + 212992);
  bf16*  wa2T    = (bf16*)(ws + 245760);
  bf16*  wc1T    = (bf16*)(ws + 249856);
  bf16*  wc2T    = (bf16*)(ws + 282624);
  float* h_state = (float*)(ws + 286720);
  bf16*  xi0     = (bf16*)(ws + 548864);       // 50.33 MB per chunk buffer
  bf16*  xi1     = (bf16*)(ws + 50880512);
  bf16*  y0      = (bf16*)(ws + 101212160);    // 16.78 MB per chunk buffer
  bf16*  y1      = (bf16*)(ws + 117989376);    // end 134.77 MB

  prep_k<<<816, 256, 0, stream>>>(hidden, dones, W_emb, Wi, Wh, Wa1, Wa2, Wc1, Wc2,
                                  wembT, wiT, whT, wa1T, wa2T, wc1T, wc2T, h_state);
  for (int cs = -1; cs <= NCHUNK; ++cs) {
    fused_k<<<2304, 256, 0, stream>>>(obs, b_emb, bi, wembT, wiT, xi0, xi1,
                                      dones, bh_n, whT, h_state, y0, y1, out_hidden,
                                      ba1, ba2, bc1, bc2, wa1T, wa2T, wc1T, wc2T,
                                      out_logits, out_v, cs);
  }
  (void)in_sizes; (void)n_in; (void)out_size; (void)ws_size;
}

// Round 4
// 906.609 us; speedup vs baseline: 1.7918x; 1.1455x over previous
//
#include <hip/hip_runtime.h>

#define T_DIM 1024
#define B_DIM 512
#define OBS_DIM 64
#define H_DIM 128
#define G3 384
#define A_DIM 16
#define CT 128
#define NCHUNK 8

typedef __bf16 bf16;
typedef __attribute__((ext_vector_type(4))) __bf16 bf16x4;
typedef __attribute__((ext_vector_type(8))) __bf16 bf16x8;
typedef __attribute__((ext_vector_type(4))) float f32x4;

#define MFMA(a, b, c) __builtin_amdgcn_mfma_f32_16x16x32_bf16((a), (b), (c), 0, 0, 0)

__device__ __forceinline__ float sigm(float x) { return 1.0f / (1.0f + __expf(-x)); }
__device__ __forceinline__ float tanh_f(float x) { return 1.0f - 2.0f / (__expf(2.0f * x) + 1.0f); }

// ---------------- prep: bf16 transposed weights + h_state init ----------------
__global__ __launch_bounds__(256) void prep_k(
    const float* __restrict__ hidden, const int* __restrict__ dones,
    const float* __restrict__ W_emb, const float* __restrict__ Wi,
    const float* __restrict__ Wh, const float* __restrict__ Wa1,
    const float* __restrict__ Wa2, const float* __restrict__ Wc1,
    const float* __restrict__ Wc2,
    bf16* __restrict__ wembT, bf16* __restrict__ wiT, bf16* __restrict__ whT,
    bf16* __restrict__ wa1T, bf16* __restrict__ wa2T, bf16* __restrict__ wc1T,
    bf16* __restrict__ wc2T, float* __restrict__ h_state) {
  int i = blockIdx.x * 256 + threadIdx.x;
  if (i < 8192) { int n = i / OBS_DIM, k = i % OBS_DIM; wembT[i] = (bf16)W_emb[k * H_DIM + n]; return; }
  i -= 8192;
  if (i < 49152) { int g = i / H_DIM, k = i % H_DIM; wiT[i] = (bf16)Wi[k * G3 + g]; return; }
  i -= 49152;
  if (i < 49152) { int g = i / H_DIM, k = i % H_DIM; whT[i] = (bf16)Wh[k * G3 + g]; return; }
  i -= 49152;
  if (i < 16384) { int n = i / H_DIM, k = i % H_DIM; wa1T[i] = (bf16)Wa1[k * H_DIM + n]; return; }
  i -= 16384;
  if (i < 2048) { int a = i / H_DIM, k = i % H_DIM; wa2T[i] = (bf16)Wa2[k * A_DIM + a]; return; }
  i -= 2048;
  if (i < 16384) { int n = i / H_DIM, k = i % H_DIM; wc1T[i] = (bf16)Wc1[k * H_DIM + n]; return; }
  i -= 16384;
  if (i < 2048) { int r = i / H_DIM, k = i % H_DIM; wc2T[i] = (r == 0) ? (bf16)Wc2[k] : (bf16)0.0f; return; }
  i -= 2048;
  if (i < 65536) { int b = i / H_DIM; h_state[i] = dones[b] ? 0.0f : hidden[i]; return; }
}

// ================= role bodies (share one 50176-B LDS block) =================

// ---- phase1 body v2: weight-stationary, 256 rows (16 row-tiles) per block ---
// Wave w holds W_emb tiles {2w,2w+1} (16 VGPR) and Wi tiles {6w..6w+5}
// (96 VGPR) in registers for the whole block. obs/emb/xi staged via LDS.
__device__ __forceinline__ void phase1_body(
    char* smem, int bid, const float* __restrict__ obs,
    const float* __restrict__ b_emb, const float* __restrict__ bi,
    const bf16* __restrict__ wembT, const bf16* __restrict__ wiT,
    bf16* __restrict__ xi, int row_base) {
  bf16 (*obs_lds)[72]  = (bf16(*)[72])smem;            // 2304 B
  bf16 (*emb_lds)[136] = (bf16(*)[136])(smem + 2304);  // 4352 B
  bf16 (*strip)[392]   = (bf16(*)[392])(smem + 6656);  // 12544 B
  int tid = threadIdx.x, wave = tid >> 6, lane = tid & 63;
  int nl = lane & 15, q = lane >> 4;

  bf16x8 we[2][2], wi_f[6][4];
  float bev[2], biv[6];
#pragma unroll
  for (int e = 0; e < 2; ++e) {
    int nt = wave * 2 + e;
#pragma unroll
    for (int kb = 0; kb < 2; ++kb)
      we[e][kb] = *(const bf16x8*)(wembT + (nt * 16 + nl) * OBS_DIM + kb * 32 + q * 8);
    bev[e] = b_emb[nt * 16 + nl];
  }
#pragma unroll
  for (int j = 0; j < 6; ++j) {
    int nt = wave * 6 + j;
#pragma unroll
    for (int kb = 0; kb < 4; ++kb)
      wi_f[j][kb] = *(const bf16x8*)(wiT + (nt * 16 + nl) * H_DIM + kb * 32 + q * 8);
    biv[j] = bi[nt * 16 + nl];
  }

  int srow = tid >> 4, scol = (tid & 15) * 4;
  for (int rt = 0; rt < 16; ++rt) {
    int r0 = bid * 256 + rt * 16;  // chunk-local row base
    {   // stage obs tile (f32 -> bf16), 256 thr x 1 float4
      const float* src = obs + ((long)row_base + r0 + srow) * OBS_DIM + scol;
      float4 vv = *(const float4*)src;
      bf16x4 b; b[0] = (bf16)vv.x; b[1] = (bf16)vv.y; b[2] = (bf16)vv.z; b[3] = (bf16)vv.w;
      *(bf16x4*)&obs_lds[srow][scol] = b;
    }
    __syncthreads();
    bf16x8 ao[2];
#pragma unroll
    for (int kb = 0; kb < 2; ++kb) ao[kb] = *(const bf16x8*)&obs_lds[nl][kb * 32 + q * 8];
#pragma unroll
    for (int e = 0; e < 2; ++e) {
      f32x4 c = {0.f, 0.f, 0.f, 0.f};
      c = MFMA(ao[0], we[e][0], c);
      c = MFMA(ao[1], we[e][1], c);
#pragma unroll
      for (int r = 0; r < 4; ++r) {
        float v = c[r] + bev[e];
        emb_lds[q * 4 + r][(wave * 2 + e) * 16 + nl] = (bf16)(v > 0.f ? v : 0.f);
      }
    }
    __syncthreads();
    bf16x8 ae[4];
#pragma unroll
    for (int kb = 0; kb < 4; ++kb) ae[kb] = *(const bf16x8*)&emb_lds[nl][kb * 32 + q * 8];
#pragma unroll
    for (int j = 0; j < 6; ++j) {
      int nt = wave * 6 + j;
      f32x4 c = {0.f, 0.f, 0.f, 0.f};
#pragma unroll
      for (int kb = 0; kb < 4; ++kb) c = MFMA(ae[kb], wi_f[j][kb], c);
      int gate = nt >> 3, dloc = (nt & 7) * 16 + nl;
      int pos = (gate < 2) ? (2 * dloc + gate) : (256 + dloc);
#pragma unroll
      for (int r = 0; r < 4; ++r) strip[q * 4 + r][pos] = (bf16)(c[r] + biv[j]);
    }
    __syncthreads();
    bf16* dst = xi + (long)r0 * G3;
#pragma unroll
    for (int it = 0; it < 3; ++it) {
      int e0 = (it * 256 + tid) * 8;
      int row = e0 / G3, col = e0 % G3;
      *(int4*)(dst + e0) = *(const int4*)&strip[row][col];
    }
  }
}

// ---- scan body: GRU over CT steps, 2 chains per block (1 block/CU) ----------
__device__ __forceinline__ void scan_body(
    char* smem, int bid, const bf16* __restrict__ xi,
    const int* __restrict__ dones, const float* __restrict__ bh_n,
    const bf16* __restrict__ whT, float* __restrict__ h_state,
    bf16* __restrict__ y, float* __restrict__ hidden_out, int chunk) {
  bf16 (*hb)[16][136]      = (bf16(*)[16][136])smem;              // 8704 B
  bf16 (*xibuf)[8][2][400] = (bf16(*)[8][2][400])(smem + 8704);   // 25600 B
  int  (*dn)[2]            = (int(*)[2])(smem + 34304);           // 1032 B

  __builtin_amdgcn_s_setprio(1);   // win SIMD arbitration vs worker waves

  int tid = threadIdx.x;
  int wave = tid >> 6, lane = tid & 63;
  int nl = lane & 15, q = lane >> 4;
  int b0 = bid * 2;
  int ch = q & 1;
  int hsel = q >> 1;
  int dim = wave * 16 + (hsel << 6) + nl;

  for (int i = tid; i < 2 * 16 * 136; i += 256) ((bf16*)hb)[i] = (bf16)0.0f;
  for (int i = tid; i <= CT; i += 256) {
    int t = chunk * CT + i;
    dn[i][0] = (t < T_DIM) ? dones[t * B_DIM + b0] : 0;
    dn[i][1] = (t < T_DIM) ? dones[t * B_DIM + b0 + 1] : 0;
  }
  int c0 = tid, c1 = 256 + tid, c2 = 512 + tid;
  int t0 = c0 / 96, p0 = c0 % 96, sc0 = p0 / 48, o0 = (p0 % 48) * 8;
  int t1 = c1 / 96, p1 = c1 % 96, sc1 = p1 / 48, o1 = (p1 % 48) * 8;
  int t2 = c2 / 96, p2 = c2 % 96, sc2 = p2 / 48, o2 = (p2 % 48) * 8;
  const long PSTR = (long)8 * B_DIM * G3;
  const bf16* pfs0 = xi + ((long)(8 + t0) * B_DIM + b0 + sc0) * G3 + o0;
  const bf16* pfs1 = xi + ((long)(8 + t1) * B_DIM + b0 + sc1) * G3 + o1;
  const bf16* pfs2 = xi + ((long)(8 + t2) * B_DIM + b0 + sc2) * G3 + o2;
  *(int4*)&xibuf[0][t0][sc0][o0] = *(const int4*)(xi + ((long)t0 * B_DIM + b0 + sc0) * G3 + o0);
  *(int4*)&xibuf[0][t1][sc1][o1] = *(const int4*)(xi + ((long)t1 * B_DIM + b0 + sc1) * G3 + o1);
  *(int4*)&xibuf[0][t2][sc2][o2] = *(const int4*)(xi + ((long)t2 * B_DIM + b0 + sc2) * G3 + o2);
  __syncthreads();

  float hprev = h_state[(b0 + ch) * H_DIM + dim];
  {
    bf16 h0 = (bf16)hprev;
    hb[0][0 + ch][dim] = h0;  hb[0][4 + ch][dim] = h0;
    hb[0][8 + ch][dim] = h0;  hb[0][12 + ch][dim] = h0;
  }
  bf16x8 wf[6][4];
#pragma unroll
  for (int g = 0; g < 3; ++g)
#pragma unroll
    for (int hI = 0; hI < 2; ++hI)
#pragma unroll
      for (int kb = 0; kb < 4; ++kb)
        wf[g * 2 + hI][kb] =
            *(const bf16x8*)(whT + ((g * 8 + wave + 4 * hI) * 16 + nl) * H_DIM + kb * 32 + q * 8);
  float bhn = bh_n[dim];
  bf16* yp = y + (long)(b0 + ch) * H_DIM + dim;
  __syncthreads();

  int4 pfr0, pfr1, pfr2;

#define BAR()                                                                  \
  do {                                                                         \
    asm volatile("s_waitcnt lgkmcnt(0)" ::: "memory");                         \
    __builtin_amdgcn_sched_barrier(0);                                         \
    __builtin_amdgcn_s_barrier();                                              \
    __builtin_amdgcn_sched_barrier(0);                                         \
  } while (0)

#define MSTEP(HA, KB)                                                          \
  do {                                                                         \
    c0_ = MFMA(HA, wf[0][KB], c0_); c1_ = MFMA(HA, wf[1][KB], c1_);            \
    c2_ = MFMA(HA, wf[2][KB], c2_); c3_ = MFMA(HA, wf[3][KB], c3_);            \
    c4_ = MFMA(HA, wf[4][KB], c4_); c5_ = MFMA(HA, wf[5][KB], c5_);            \
  } while (0)

#define GSTEP(CUR, TS, TB, PF)                                                 \
  do {                                                                         \
    const int p_ = (TS) & 1;                                                   \
    bf16x8 ha0 = *(const bf16x8*)&hb[p_][nl][0 * 32 + q * 8];                  \
    bf16x8 ha1 = *(const bf16x8*)&hb[p_][nl][1 * 32 + q * 8];                  \
    bf16x8 ha2 = *(const bf16x8*)&hb[p_][nl][2 * 32 + q * 8];                  \
    bf16x8 ha3 = *(const bf16x8*)&hb[p_][nl][3 * 32 + q * 8];                  \
    const bf16* xrow_ = &xibuf[CUR][TS][ch][0];                                \
    unsigned urz_ = *(const unsigned*)(xrow_ + 2 * dim);                       \
    float xnv_ = (float)xrow_[256 + dim];                                      \
    int dnv_ = dn[(TB) + (TS) + 1][ch];                                        \
    if ((TS) == 0 && (PF)) {                                                   \
      pfr0 = *(const int4*)pfs0; pfs0 += PSTR;                                 \
      pfr1 = *(const int4*)pfs1; pfs1 += PSTR;                                 \
      pfr2 = *(const int4*)pfs2; pfs2 += PSTR;                                 \
    }                                                                          \
    f32x4 c0_ = {0.f, 0.f, 0.f, 0.f}, c1_ = {0.f, 0.f, 0.f, 0.f};             \
    f32x4 c2_ = {0.f, 0.f, 0.f, 0.f}, c3_ = {0.f, 0.f, 0.f, 0.f};             \
    f32x4 c4_ = {0.f, 0.f, 0.f, 0.f}, c5_ = {0.f, 0.f, 0.f, 0.f};             \
    MSTEP(ha0, 0); MSTEP(ha1, 1); MSTEP(ha2, 2); MSTEP(ha3, 3);                \
    if ((TS) == 7 && (PF)) {                                                   \
      *(int4*)&xibuf[(CUR) ^ 1][t0][sc0][o0] = pfr0;                           \
      *(int4*)&xibuf[(CUR) ^ 1][t1][sc1][o1] = pfr1;                           \
      *(int4*)&xibuf[(CUR) ^ 1][t2][sc2][o2] = pfr2;                           \
    }                                                                          \
    float hr_ = hsel ? (ch ? c1_[1] : c1_[0]) : (ch ? c0_[1] : c0_[0]);        \
    float hz_ = hsel ? (ch ? c3_[1] : c3_[0]) : (ch ? c2_[1] : c2_[0]);        \
    float hn_ = hsel ? (ch ? c5_[1] : c5_[0]) : (ch ? c4_[1] : c4_[0]);        \
    union { unsigned u; float f; } cvr_, cvz_;                                 \
    cvr_.u = urz_ << 16; cvz_.u = urz_ & 0xffff0000u;                          \
    float r_ = sigm(cvr_.f + hr_);                                             \
    float z_ = sigm(cvz_.f + hz_);                                             \
    float n_ = tanh_f(xnv_ + r_ * (hn_ + bhn));                                \
    float hnew_ = (1.0f - z_) * n_ + z_ * hprev;                               \
    float heff_ = dnv_ ? 0.0f : hnew_;                                         \
    *yp = (bf16)hnew_; yp += B_DIM * H_DIM;                                    \
    bf16 hbv_ = (bf16)heff_;                                                   \
    hb[p_ ^ 1][0 + ch][dim] = hbv_;  hb[p_ ^ 1][4 + ch][dim] = hbv_;           \
    hb[p_ ^ 1][8 + ch][dim] = hbv_;  hb[p_ ^ 1][12 + ch][dim] = hbv_;          \
    hprev = heff_;                                                             \
    BAR();                                                                     \
  } while (0)

  for (int tb = 0; tb < CT; tb += 16) {
    GSTEP(0, 0, tb, 1); GSTEP(0, 1, tb, 1); GSTEP(0, 2, tb, 1); GSTEP(0, 3, tb, 1);
    GSTEP(0, 4, tb, 1); GSTEP(0, 5, tb, 1); GSTEP(0, 6, tb, 1); GSTEP(0, 7, tb, 1);
    const int pfB = (tb + 16 < CT) ? 1 : 0;
    GSTEP(1, 0, tb + 8, pfB); GSTEP(1, 1, tb + 8, pfB); GSTEP(1, 2, tb + 8, pfB);
    GSTEP(1, 3, tb + 8, pfB); GSTEP(1, 4, tb + 8, pfB); GSTEP(1, 5, tb + 8, pfB);
    GSTEP(1, 6, tb + 8, pfB); GSTEP(1, 7, tb + 8, pfB);
  }
#undef GSTEP
#undef MSTEP
#undef BAR
  __builtin_amdgcn_s_setprio(0);

  h_state[(b0 + ch) * H_DIM + dim] = hprev;
  if (chunk == NCHUNK - 1) hidden_out[(b0 + ch) * H_DIM + dim] = hprev;
}

// ---- heads body v2: weight-stationary, 256 rows (16 row-tiles) per block ----
// Wave w holds Wa1 tiles {2w,2w+1}, Wc1 tiles {2w,2w+1}, plus Wa2/Wc2 (96
// VGPR total). y staged via LDS; a1/c1 strips shared; wave0 -> logits,
// wave1 -> v.
__device__ __forceinline__ void heads_body(
    char* smem, int bid, const bf16* __restrict__ y,
    const float* __restrict__ ba1, const float* __restrict__ ba2,
    const float* __restrict__ bc1, const float* __restrict__ bc2,
    const bf16* __restrict__ wa1T, const bf16* __restrict__ wa2T,
    const bf16* __restrict__ wc1T, const bf16* __restrict__ wc2T,
    float* __restrict__ logits, float* __restrict__ v, int t_base) {
  bf16  (*y_lds)[136] = (bf16(*)[136])smem;              // 4352 B
  bf16  (*a1s)[136]   = (bf16(*)[136])(smem + 4352);     // 4352 B
  bf16  (*c1s)[136]   = (bf16(*)[136])(smem + 8704);     // 4352 B
  float (*s_o)[16]    = (float(*)[16])(smem + 13056);    // 1024 B
  float (*s_v)        = (float*)(smem + 14080);          // 64 B
  int tid = threadIdx.x, wave = tid >> 6, lane = tid & 63;
  int nl = lane & 15, q = lane >> 4;

  bf16x8 wa1f[2][4], wc1f[2][4], wa2f[4], wc2f[4];
  float ba1v[2], bc1v[2];
#pragma unroll
  for (int e = 0; e < 2; ++e) {
    int nt = wave * 2 + e;
#pragma unroll
    for (int kb = 0; kb < 4; ++kb) {
      wa1f[e][kb] = *(const bf16x8*)(wa1T + (nt * 16 + nl) * H_DIM + kb * 32 + q * 8);
      wc1f[e][kb] = *(const bf16x8*)(wc1T + (nt * 16 + nl) * H_DIM + kb * 32 + q * 8);
    }
    ba1v[e] = ba1[nt * 16 + nl];
    bc1v[e] = bc1[nt * 16 + nl];
  }
#pragma unroll
  for (int kb = 0; kb < 4; ++kb) {
    wa2f[kb] = *(const bf16x8*)(wa2T + nl * H_DIM + kb * 32 + q * 8);
    wc2f[kb] = *(const bf16x8*)(wc2T + nl * H_DIM + kb * 32 + q * 8);
  }
  float ba2v = ba2[nl], bc2v = bc2[0];

  int srow = tid >> 4, scol = (tid & 15) * 8;
  for (int rt = 0; rt < 16; ++rt) {
    int r0 = bid * 256 + rt * 16;          // chunk-local row base
    long gr0 = (long)t_base * B_DIM + r0;  // global row base
    // stage y tile: 256 thr x int4
    *(int4*)&y_lds[srow][scol] = *(const int4*)(y + (long)(r0 + srow) * H_DIM + scol);
    __syncthreads();
    bf16x8 ya[4];
#pragma unroll
    for (int kb = 0; kb < 4; ++kb) ya[kb] = *(const bf16x8*)&y_lds[nl][kb * 32 + q * 8];
#pragma unroll
    for (int e = 0; e < 2; ++e) {
      f32x4 ca = {0.f, 0.f, 0.f, 0.f}, cc = {0.f, 0.f, 0.f, 0.f};
#pragma unroll
      for (int kb = 0; kb < 4; ++kb) {
        ca = MFMA(ya[kb], wa1f[e][kb], ca);
        cc = MFMA(ya[kb], wc1f[e][kb], cc);
      }
      int colb = (wave * 2 + e) * 16 + nl;
#pragma unroll
      for (int r = 0; r < 4; ++r) {
        float va = ca[r] + ba1v[e];
        float vc = cc[r] + bc1v[e];
        a1s[q * 4 + r][colb] = (bf16)(va > 0.f ? va : 0.f);
        c1s[q * 4 + r][colb] = (bf16)(vc > 0.f ? vc : 0.f);
      }
    }
    __syncthreads();
    if (wave == 0) {
      bf16x8 a1f[4];
#pragma unroll
      for (int kb = 0; kb < 4; ++kb) a1f[kb] = *(const bf16x8*)&a1s[nl][kb * 32 + q * 8];
      f32x4 c = {0.f, 0.f, 0.f, 0.f};
#pragma unroll
      for (int kb = 0; kb < 4; ++kb) c = MFMA(a1f[kb], wa2f[kb], c);
#pragma unroll
      for (int r = 0; r < 4; ++r) s_o[q * 4 + r][nl] = c[r] + ba2v;
    } else if (wave == 1) {
      bf16x8 c1f[4];
#pragma unroll
      for (int kb = 0; kb < 4; ++kb) c1f[kb] = *(const bf16x8*)&c1s[nl][kb * 32 + q * 8];
      f32x4 c = {0.f, 0.f, 0.f, 0.f};
#pragma unroll
      for (int kb = 0; kb < 4; ++kb) c = MFMA(c1f[kb], wc2f[kb], c);
      if (nl == 0) {
#pragma unroll
        for (int r = 0; r < 4; ++r) s_v[q * 4 + r] = c[r] + bc2v;
      }
    }
    __syncthreads();
    if (tid < 64) {
      *(int4*)(logits + gr0 * A_DIM + tid * 4) = *(const int4*)&s_o[tid >> 2][(tid & 3) * 4];
    } else if (tid < 80) {
      v[gr0 + (tid - 64)] = s_v[tid - 64];
    }
  }
}

// ---- fused pipeline kernel: scan(cs) ∥ phase1(cs+1) ∥ heads(cs-1) ------------
// 768 blocks = 3 blocks/CU (LDS-limited): 1 scan + 1 phase1 + 1 heads per CU.
__global__ __launch_bounds__(256, 3) void fused_k(
    const float* __restrict__ obs, const float* __restrict__ b_emb,
    const float* __restrict__ bi, const bf16* __restrict__ wembT,
    const bf16* __restrict__ wiT, bf16* __restrict__ xi0, bf16* __restrict__ xi1,
    const int* __restrict__ dones, const float* __restrict__ bh_n,
    const bf16* __restrict__ whT, float* __restrict__ h_state,
    bf16* __restrict__ y0, bf16* __restrict__ y1, float* __restrict__ hidden_out,
    const float* __restrict__ ba1, const float* __restrict__ ba2,
    const float* __restrict__ bc1, const float* __restrict__ bc2,
    const bf16* __restrict__ wa1T, const bf16* __restrict__ wa2T,
    const bf16* __restrict__ wc1T, const bf16* __restrict__ wc2T,
    float* __restrict__ logits, float* __restrict__ v, int cs) {
  __shared__ __align__(16) char smem[50176];
  int bid = blockIdx.x;
  if (bid < 256) {
    if (cs >= 0 && cs < NCHUNK)
      scan_body(smem, bid, (cs & 1) ? xi1 : xi0, dones, bh_n, whT, h_state,
                (cs & 1) ? y1 : y0, hidden_out, cs);
    return;
  }
  if (bid < 512) {
    int cp = cs + 1;
    if (cp >= 0 && cp < NCHUNK)
      phase1_body(smem, bid - 256, obs, b_emb, bi, wembT, wiT,
                  (cp & 1) ? xi1 : xi0, cp * CT * B_DIM);
    return;
  }
  {
    int ch2 = cs - 1;
    if (ch2 >= 0 && ch2 < NCHUNK)
      heads_body(smem, bid - 512, (ch2 & 1) ? y1 : y0, ba1, ba2, bc1, bc2,
                 wa1T, wa2T, wc1T, wc2T, logits, v, ch2 * CT);
  }
}

// ---------------- launch ------------------------------------------------------
extern "C" void kernel_launch(void* const* d_in, const int* in_sizes, int n_in,
                              void* d_out, int out_size, void* d_ws, size_t ws_size,
                              hipStream_t stream) {
  const float* hidden = (const float*)d_in[0];
  const float* obs    = (const float*)d_in[1];
  const int*   dones  = (const int*)d_in[2];
  const float* W_emb  = (const float*)d_in[3];
  const float* b_emb  = (const float*)d_in[4];
  const float* Wi     = (const float*)d_in[5];
  const float* bi     = (const float*)d_in[6];
  const float* Wh     = (const float*)d_in[7];
  const float* bh_n   = (const float*)d_in[8];
  const float* Wa1    = (const float*)d_in[9];
  const float* ba1    = (const float*)d_in[10];
  const float* Wa2    = (const float*)d_in[11];
  const float* ba2    = (const float*)d_in[12];
  const float* Wc1    = (const float*)d_in[13];
  const float* bc1    = (const float*)d_in[14];
  const float* Wc2    = (const float*)d_in[15];
  const float* bc2    = (const float*)d_in[16];

  float* out_hidden = (float*)d_out;
  float* out_logits = out_hidden + B_DIM * H_DIM;
  float* out_v      = out_logits + (long)T_DIM * B_DIM * A_DIM;

  char* ws = (char*)d_ws;
  bf16*  wembT   = (bf16*)(ws + 0);
  bf16*  wiT     = (bf16*)(ws + 16384);
  bf16*  whT     = (bf16*)(ws + 114688);
  bf16*  wa1T    = (bf16*)(ws + 212992);
  bf16*  wa2T    = (bf16*)(ws + 245760);
  bf16*  wc1T    = (bf16*)(ws + 249856);
  bf16*  wc2T    = (bf16*)(ws + 282624);
  float* h_state = (float*)(ws + 286720);
  bf16*  xi0     = (bf16*)(ws + 548864);       // 50.33 MB per chunk buffer
  bf16*  xi1     = (bf16*)(ws + 50880512);
  bf16*  y0      = (bf16*)(ws + 101212160);    // 16.78 MB per chunk buffer
  bf16*  y1      = (bf16*)(ws + 117989376);    // end 134.77 MB

  prep_k<<<816, 256, 0, stream>>>(hidden, dones, W_emb, Wi, Wh, Wa1, Wa2, Wc1, Wc2,
                                  wembT, wiT, whT, wa1T, wa2T, wc1T, wc2T, h_state);
  for (int cs = -1; cs <= NCHUNK; ++cs) {
    fused_k<<<768, 256, 0, stream>>>(obs, b_emb, bi, wembT, wiT, xi0, xi1,
                                     dones, bh_n, whT, h_state, y0, y1, out_hidden,
                                     ba1, ba2, bc1, bc2, wa1T, wa2T, wc1T, wc2T,
                                     out_logits, out_v, cs);
  }
  (void)in_sizes; (void)n_in; (void)out_size; (void)ws_size;
}